// Round 11
// baseline (417.039 us; speedup 1.0000x reference)
//
#include <hip/hip_runtime.h>
#include <math.h>

#define BN_EPS 1e-5f

// ---------------------------------------------------------------------------
// Weight transpose: w[co][ci][kh][kw] -> wt[ci][kpos][co] (co fastest) so
// lane=co weight loads are coalesced 256B dword loads.
// ---------------------------------------------------------------------------
__global__ void wtrans_kernel(const float* __restrict__ w, float* __restrict__ wt) {
    int i = blockIdx.x * 256 + threadIdx.x;
    if (i >= 128 * 128 * 9) return;
    int co = i / 1152;
    int rem = i - co * 1152;
    int ci = rem / 9;
    int kpos = rem - ci * 9;
    wt[ci * 1152 + kpos * 128 + co] = w[i];
}

// ---------------------------------------------------------------------------
// Pad x: [16,128,32,32] -> [16,128,34,36] with zero halo (rows/cols -1..32;
// cols 34,35 are alignment slack, never read).
// ---------------------------------------------------------------------------
__global__ void pad_x_kernel(const float* __restrict__ x, float* __restrict__ xp) {
    const int plane = blockIdx.x;            // n*128 + ci
    const float* sp = x + (size_t)plane * 1024;
    float* dp = xp + (size_t)plane * 1224;
    for (int e = threadIdx.x; e < 1224; e += 256) {
        const int pr = e / 36, pc = e - pr * 36;
        const int r = pr - 1, c = pc - 1;
        float v = 0.f;
        if ((unsigned)r < 32u && (unsigned)c < 32u) v = sp[r * 32 + c];
        dp[e] = v;
    }
}

// Zero only the border cells of a padded buffer (interior written by combine).
__global__ void zero_borders_kernel(float* __restrict__ yp) {
    const int plane = blockIdx.x;            // 2048
    float* dp = yp + (size_t)plane * 1224;
    const int t = threadIdx.x;               // 256 threads, 136 used
    if (t < 36) dp[t] = 0.f;                            // padded row 0
    else if (t < 72) dp[33 * 36 + (t - 36)] = 0.f;      // padded row 33
    else if (t < 104) dp[(t - 71) * 36] = 0.f;          // rows 1..32, col 0
    else if (t < 136) dp[(t - 103) * 36 + 33] = 0.f;    // rows 1..32, col 33
}

// ---------------------------------------------------------------------------
// Register-only AdderNet conv helpers (padded source -> unconditional loads).
// 8-px window: R[0..9] = padded cols c0..c0+9.
// ---------------------------------------------------------------------------
__device__ __forceinline__ void load_rowP8(float (&R)[10], const float* rp) {
    float4 q0 = *(const float4*)(rp);
    float4 q1 = *(const float4*)(rp + 4);
    float2 q2 = *(const float2*)(rp + 8);
    R[0] = q0.x; R[1] = q0.y; R[2] = q0.z; R[3] = q0.w;
    R[4] = q1.x; R[5] = q1.y; R[6] = q1.z; R[7] = q1.w;
    R[8] = q2.x; R[9] = q2.y;
}

__device__ __forceinline__ void kh_acc8(float (&acc)[8], const float (&R)[10],
                                        float w0, float w1, float w2) {
#pragma unroll
    for (int j = 0; j < 8; ++j)
        acc[j] += fabsf(R[j] - w0) + fabsf(R[j + 1] - w1) + fabsf(R[j + 2] - w2);
}

// ---------------------------------------------------------------------------
// AdderNet conv (3x3, pad 1), PARTIAL over half the ci range. Register-only:
// no LDS, no barriers, no SMEM, no conditionals in the hot loop.
// Grid: 2048 blocks 1D, XCD swizzle (bid&7 -> n pair) for L2 residency:
//   slot = bid>>3: nbit(1) | half(1) | cohalf(1) | row(5)  -> 256 slots/XCD.
// Block: 256 thr = 4 waves = 4 px-quads (8 px each), one co-half. lane = co.
// Wave: one row x 8 px x 64 co; acc[8]/lane. ~47 live floats -> ~70 VGPR,
// 8 blocks/CU -> 32 waves/CU nominal (2x r10's 16; r10 duty was ~30%).
// Per plane: 3x {kh_acc8 (48 VALU); reload rowbuf for p+1; reload 3 weights}.
// Output: positive partial sums, co-fastest layout [n][row][px][co].
// ---------------------------------------------------------------------------
__global__ __launch_bounds__(256, 2) void adder_conv_part(
    const float* __restrict__ src,   // PADDED [16,128,34,36]
    const float* __restrict__ wt,    // [ci][9][co]
    float* __restrict__ dst0, float* __restrict__ dst1) {
    const int t = threadIdx.x;
    const int lane = t & 63;
    const int q = t >> 6;                 // px quad: cols 8q..8q+7

    // XCD-aware decode: bid%8 = XCD (round-robin dispatch).
    const int bid = blockIdx.x;
    const int xcd = bid & 7;
    const int slot = bid >> 3;            // 0..255
    const int nbit = slot >> 7;           // 0..1
    const int rem = slot & 127;
    const int half = rem >> 6;            // ci half
    const int cohalf = (rem >> 5) & 1;
    const int row = rem & 31;
    const int n = xcd * 2 + nbit;

    const int c0 = q << 3;
    const int co = (cohalf << 6) + lane;

    const float* sbase = src + ((size_t)n * 128 + half * 64) * 1224;
    const float* wbase = wt + (size_t)half * 64 * 1152 + co;

    const int offA = row * 36 + c0;       // padded row 'row' = x row row-1
    const int offB = offA + 36;
    const int offC = offB + 36;

    float acc[8];
#pragma unroll
    for (int j = 0; j < 8; ++j) acc[j] = 0.f;

    float A[10], B[10], C[10];
    float wa0, wa1, wa2, wb0, wb1, wb2, wc0, wc1, wc2;

    load_rowP8(A, sbase + offA);
    load_rowP8(B, sbase + offB);
    load_rowP8(C, sbase + offC);
    wa0 = wbase[0];   wa1 = wbase[128];  wa2 = wbase[256];
    wb0 = wbase[384]; wb1 = wbase[512];  wb2 = wbase[640];
    wc0 = wbase[768]; wc1 = wbase[896];  wc2 = wbase[1024];

#pragma unroll 1
    for (int p = 0; p < 64; ++p) {
        const int pn = (p + 1 < 64) ? p + 1 : 63;   // clamped prefetch plane
        const float* sp = sbase + pn * 1224;
        const float* wp = wbase + pn * 1152;
        kh_acc8(acc, A, wa0, wa1, wa2);
        load_rowP8(A, sp + offA);
        wa0 = wp[0];   wa1 = wp[128];  wa2 = wp[256];
        kh_acc8(acc, B, wb0, wb1, wb2);
        load_rowP8(B, sp + offB);
        wb0 = wp[384]; wb1 = wp[512];  wb2 = wp[640];
        kh_acc8(acc, C, wc0, wc1, wc2);
        load_rowP8(C, sp + offC);
        wc0 = wp[768]; wc1 = wp[896];  wc2 = wp[1024];
    }

    // Epilogue: coalesced stores, co-fastest partial layout.
    float* dst = half ? dst1 : dst0;
    float* dp = dst + (((size_t)n * 32 + row) * 32 + c0) * 128 + co;
#pragma unroll
    for (int j = 0; j < 8; ++j) dp[j * 128] = acc[j];
}

// ---------------------------------------------------------------------------
// Combine + transpose: partials [n][row][px][co] -> out [n][co][row][px]
// (PADDED=true writes into [n][co][34][36] interior). out = BN(-(pA+pB))
// (+ReLU). Block per (row, n); LDS 32x129 tile.
// ---------------------------------------------------------------------------
template <bool RELU, bool PADDED>
__global__ void combine_bn_t(const float* __restrict__ pA, const float* __restrict__ pB,
                             const float* __restrict__ gamma, const float* __restrict__ beta,
                             const float* __restrict__ mean, const float* __restrict__ var,
                             float* __restrict__ out) {
    const int t = threadIdx.x;
    const int row = blockIdx.x;   // 0..31
    const int n = blockIdx.y;     // 0..15
    __shared__ float tile[32 * 129];
    const size_t base = (((size_t)n * 32 + row) * 32) * 128;  // + px*128 + co

    const int co = t & 127, th = t >> 7;
    const float iv = gamma[co] * rsqrtf(var[co] + BN_EPS);
    const float bb = beta[co] - mean[co] * iv;
#pragma unroll
    for (int e = 0; e < 16; ++e) {
        const int px = e * 2 + th;
        const size_t idx = base + px * 128 + co;
        float z = bb - (pA[idx] + pB[idx]) * iv;
        if (RELU) z = fmaxf(z, 0.f);
        tile[px * 129 + co] = z;
    }
    __syncthreads();
#pragma unroll
    for (int e = 0; e < 4; ++e) {
        const int qidx = e * 256 + t;        // 0..1023 = 128co x 8quads
        const int oco = qidx >> 3, q = qidx & 7;
        float4 v;
        v.x = tile[(4 * q + 0) * 129 + oco];
        v.y = tile[(4 * q + 1) * 129 + oco];
        v.z = tile[(4 * q + 2) * 129 + oco];
        v.w = tile[(4 * q + 3) * 129 + oco];
        if (PADDED) {
            float* op = &out[(((size_t)n * 128 + oco) * 34 + row + 1) * 36 + 1 + 4 * q];
            op[0] = v.x; op[1] = v.y; op[2] = v.z; op[3] = v.w;
        } else {
            *(float4*)&out[(((size_t)n * 128 + oco) * 32 + row) * 32 + 4 * q] = v;
        }
    }
}

// ---------------------------------------------------------------------------
// Per-(n,c) spatial mean of z (standard layout): [16,128,32,32] -> [16,128]
// ---------------------------------------------------------------------------
__global__ void mean_kernel(const float* __restrict__ z, float* __restrict__ means) {
    const int b = blockIdx.x;  // n*128 + c
    const float4 v = ((const float4*)(z + (size_t)b * 1024))[threadIdx.x];
    float sum = v.x + v.y + v.z + v.w;
#pragma unroll
    for (int o = 32; o > 0; o >>= 1) sum += __shfl_down(sum, o);
    __shared__ float ws_[4];
    if ((threadIdx.x & 63) == 0) ws_[threadIdx.x >> 6] = sum;
    __syncthreads();
    if (threadIdx.x == 0)
        means[b] = (ws_[0] + ws_[1] + ws_[2] + ws_[3]) * (1.f / 1024.f);
}

// ---------------------------------------------------------------------------
// SE gate: s = sigmoid(fc2(relu(fc1(mean)+b1))+b2), per image n.
// ---------------------------------------------------------------------------
__global__ void se_kernel(const float* __restrict__ means,
                          const float* __restrict__ fc1w, const float* __restrict__ fc1b,
                          const float* __restrict__ fc2w, const float* __restrict__ fc2b,
                          float* __restrict__ s) {
    const int n = blockIdx.x;     // 16 blocks, 128 threads
    const int t = threadIdx.x;
    __shared__ float m[128], rr[8];
    m[t] = means[n * 128 + t];
    __syncthreads();
    if (t < 8) {
        float a = fc1b[t];
        for (int c2 = 0; c2 < 128; ++c2) a += fc1w[t * 128 + c2] * m[c2];
        rr[t] = fmaxf(a, 0.f);
    }
    __syncthreads();
    float a = fc2b[t];
#pragma unroll
    for (int j = 0; j < 8; ++j) a += fc2w[t * 8 + j] * rr[j];
    s[n * 128 + t] = 1.f / (1.f + expf(-a));
}

// ---------------------------------------------------------------------------
// Final: out = relu(z * s[n,c] + x), vectorized float4 (standard layouts).
// ---------------------------------------------------------------------------
__global__ void final_kernel(const float* __restrict__ z, const float* __restrict__ x,
                             const float* __restrict__ s, float* __restrict__ out) {
    const int i = blockIdx.x * 256 + threadIdx.x;   // float4 index, 524288 total
    const int plane = i >> 8;                        // 256 float4 per (n,c)
    const float sc = s[plane];
    const float4 zv = ((const float4*)z)[i];
    const float4 xv = ((const float4*)x)[i];
    float4 o;
    o.x = fmaxf(zv.x * sc + xv.x, 0.f);
    o.y = fmaxf(zv.y * sc + xv.y, 0.f);
    o.z = fmaxf(zv.z * sc + xv.z, 0.f);
    o.w = fmaxf(zv.w * sc + xv.w, 0.f);
    ((float4*)out)[i] = o;
}

// ---------------------------------------------------------------------------
extern "C" void kernel_launch(void* const* d_in, const int* in_sizes, int n_in,
                              void* d_out, int out_size, void* d_ws, size_t ws_size,
                              hipStream_t stream) {
    const float* x    = (const float*)d_in[0];
    const float* w1   = (const float*)d_in[1];
    const float* g1   = (const float*)d_in[2];
    const float* b1   = (const float*)d_in[3];
    const float* m1   = (const float*)d_in[4];
    const float* v1   = (const float*)d_in[5];
    const float* w2   = (const float*)d_in[6];
    const float* g2   = (const float*)d_in[7];
    const float* b2   = (const float*)d_in[8];
    const float* m2   = (const float*)d_in[9];
    const float* v2   = (const float*)d_in[10];
    const float* fc1w = (const float*)d_in[11];
    const float* fc1b = (const float*)d_in[12];
    const float* fc2w = (const float*)d_in[13];
    const float* fc2b = (const float*)d_in[14];
    float* out = (float*)d_out;

    float* ws    = (float*)d_ws;
    float* wt1   = ws;                   // 147456
    float* wt2   = wt1 + 147456;         // 147456
    float* xp    = wt2 + 147456;         // 2506752 (padded x; later reused as z)
    float* yp    = xp + 2506752;         // 2506752 (padded y)
    float* pA    = yp + 2506752;         // 2097152 (split-0 partial, co-fast)
    float* pB    = pA + 2097152;         // 2097152 (split-1 partial, co-fast)
    float* means = pB + 2097152;         // 2048
    float* s     = means + 2048;         // 2048
    float* z     = xp;                   // xp dead after conv1 -> reuse for z

    wtrans_kernel<<<576, 256, 0, stream>>>(w1, wt1);
    wtrans_kernel<<<576, 256, 0, stream>>>(w2, wt2);
    pad_x_kernel<<<2048, 256, 0, stream>>>(x, xp);
    zero_borders_kernel<<<2048, 256, 0, stream>>>(yp);

    dim3 tgrid(32, 16);
    // Conv1 partials -> pA/pB; combine+transpose -> yp (padded, +ReLU).
    adder_conv_part<<<2048, 256, 0, stream>>>(xp, wt1, pA, pB);
    combine_bn_t<true, true ><<<tgrid, 256, 0, stream>>>(pA, pB, g1, b1, m1, v1, yp);
    // Conv2 partials (src = yp) -> pA/pB; combine+transpose -> z (standard).
    adder_conv_part<<<2048, 256, 0, stream>>>(yp, wt2, pA, pB);
    combine_bn_t<false, false><<<tgrid, 256, 0, stream>>>(pA, pB, g2, b2, m2, v2, z);

    mean_kernel<<<2048, 256, 0, stream>>>(z, means);
    se_kernel<<<16, 128, 0, stream>>>(means, fc1w, fc1b, fc2w, fc2b, s);
    final_kernel<<<2048, 256, 0, stream>>>(z, x, s, out);
}